// Round 11
// baseline (214.753 us; speedup 1.0000x reference)
//
#include <hip/hip_runtime.h>
#include <hip/hip_fp16.h>

#define N_NODES 10000
#define N_EDGES 640000
#define N_GRAPHS 64
#define FEATS 128

#define NSLICE 64
#define EPS (N_EDGES / NSLICE)   // 10000 edges per slice
#define CAP 160                  // padded per-node edge capacity (max in-deg ~112)

static inline size_t align_up(size_t x, size_t a) { return (x + a - 1) & ~(a - 1); }

// ---------------------------------------------------------------------------
// 1) HIST: blocks 0..63 histogram dst-slice b into counts[b][*];
//    blocks 64..127 histogram src-slice (b-64) into scounts[b-64][*].
__global__ __launch_bounds__(256) void hist_kernel(const int* __restrict__ src,
                                                   const int* __restrict__ dst,
                                                   int* __restrict__ counts,
                                                   int* __restrict__ scounts) {
    __shared__ int h[N_NODES];
    const int tid = threadIdx.x;
    const int b = blockIdx.x;
    const bool is_dst = (b < NSLICE);
    const int slice = is_dst ? b : b - NSLICE;
    const int* col = is_dst ? dst : src;
    int* outp = (is_dst ? counts : scounts) + slice * N_NODES;

    for (int i = tid; i < N_NODES; i += 256) h[i] = 0;
    __syncthreads();
    const int4* c4 = (const int4*)(col + slice * EPS);
    for (int i = tid; i < EPS / 4; i += 256) {
        int4 v = c4[i];
        atomicAdd(&h[v.x], 1);
        atomicAdd(&h[v.y], 1);
        atomicAdd(&h[v.z], 1);
        atomicAdd(&h[v.w], 1);
    }
    __syncthreads();
    for (int i = tid; i < N_NODES; i += 256) outp[i] = h[i];
}

// ---------------------------------------------------------------------------
// 2) DEGNORM+BASE+PRESCALE: per node n, scan counts along slices in-place
//    into write bases seeded with n*CAP; deg_in / norms / graph counts; then
//    the block prescales its own 256 nodes: xs = fp16(in_feat * norm_src).
__global__ __launch_bounds__(256) void degnorm_base_kernel(int* __restrict__ counts,
                                                           const int* __restrict__ scounts,
                                                           const int* __restrict__ gids,
                                                           const float* __restrict__ in_feat,
                                                           int* __restrict__ deg_in,
                                                           float* __restrict__ norm_src,
                                                           float* __restrict__ norm_dst,
                                                           int* __restrict__ graph_cnt,
                                                           __half* __restrict__ xs) {
    __shared__ int gcnt[N_GRAPHS];
    __shared__ float ns_l[256];
    const int tid = threadIdx.x;
    const int base_n = blockIdx.x * 256;
    if (tid < N_GRAPHS) gcnt[tid] = 0;
    __syncthreads();
    int n = base_n + tid;
    float ns = 0.f;
    if (n < N_NODES) {
        int run = n * CAP;
        for (int s = 0; s < NSLICE; s++) {
            int c = counts[s * N_NODES + n];
            counts[s * N_NODES + n] = run;
            run += c;
        }
        int di = run - n * CAP;
        int dou = 0;
        for (int s = 0; s < NSLICE; s++) dou += scounts[s * N_NODES + n];
        deg_in[n] = di;
        norm_dst[n] = rsqrtf((float)(di < 1 ? 1 : di));
        ns = rsqrtf((float)(dou < 1 ? 1 : dou));
        norm_src[n] = ns;
        atomicAdd(&gcnt[gids[n]], 1);
    }
    ns_l[tid] = ns;
    __syncthreads();
    if (tid < N_GRAPHS && gcnt[tid]) atomicAdd(&graph_cnt[tid], gcnt[tid]);

    // prescale this block's 256 nodes (coalesced: 32 consecutive lanes per node)
    const float4* inf4 = (const float4*)in_feat;
    for (int i = tid; i < 256 * 32; i += 256) {
        int nloc = i >> 5;
        int n2 = base_n + nloc;
        if (n2 < N_NODES) {
            float4 v = inf4[(size_t)n2 * 32 + (i & 31)];
            float s = ns_l[nloc];
            __half2 h0 = __floats2half2_rn(v.x * s, v.y * s);
            __half2 h1 = __floats2half2_rn(v.z * s, v.w * s);
            __half2* o = (__half2*)(xs + (size_t)n2 * FEATS + (i & 31) * 4);
            o[0] = h0; o[1] = h1;
        }
    }
}

// ---------------------------------------------------------------------------
// 3) SCATTER: block s places its EPS edges via LDS cursors into the padded CSR.
__global__ __launch_bounds__(256) void scatter_kernel(const int* __restrict__ src,
                                                      const int* __restrict__ dst,
                                                      const int* __restrict__ base,
                                                      int* __restrict__ sorted_src) {
    __shared__ int cur[N_NODES];
    const int tid = threadIdx.x;
    const int s = blockIdx.x;
    for (int i = tid; i < N_NODES; i += 256) cur[i] = base[s * N_NODES + i];
    __syncthreads();
    const int4* s4 = (const int4*)(src + s * EPS);
    const int4* d4 = (const int4*)(dst + s * EPS);
    for (int i = tid; i < EPS / 4; i += 256) {
        int4 sv = s4[i];
        int4 dv = d4[i];
        int p;
        p = atomicAdd(&cur[dv.x], 1); sorted_src[p] = sv.x;
        p = atomicAdd(&cur[dv.y], 1); sorted_src[p] = sv.y;
        p = atomicAdd(&cur[dv.z], 1); sorted_src[p] = sv.z;
        p = atomicAdd(&cur[dv.w], 1); sorted_src[p] = sv.w;
    }
}

// ---------------------------------------------------------------------------
// 4) AGGREGATE (fp16 in, fp32 out): one wave per dst node. Quarter-wave
//    (16 lanes x 16 B) fetches one 256 B fp16 row per instr -> 4 edges per
//    wave instruction; unroll x4 keeps 16 rows (4 KB) in flight per wave.
//    (R10's 4-nodes-per-wave fusion regressed: quarter-wave-per-node walks
//    4x more edges serially with 4x fewer waves — keep 1 wave per node.)
__global__ __launch_bounds__(256) void aggregate_kernel(const __half* __restrict__ X,
                                                        const int* __restrict__ sorted_src,
                                                        const int* __restrict__ deg_in,
                                                        const float* __restrict__ norm_dst,
                                                        float* __restrict__ out) {
    const int tid = threadIdx.x;
    const int wave = tid >> 6, lane = tid & 63;
    const int grp = lane >> 4, l16 = lane & 15;
    const int n = blockIdx.x * 4 + wave;
    const int start = n * CAP;
    const int cnt = deg_in[n];
    const uint4* __restrict__ x4 = (const uint4*)X;  // row = 16 uint4 (256 B)
    float acc[8] = {0.f, 0.f, 0.f, 0.f, 0.f, 0.f, 0.f, 0.f};

    // group `grp` handles edges congruent to `grp` (mod 4)
    int c = grp;
    for (; c + 12 < cnt; c += 16) {
        int idx[4];
#pragma unroll
        for (int k = 0; k < 4; k++) idx[k] = sorted_src[start + c + 4 * k];
        uint4 v[4];
#pragma unroll
        for (int k = 0; k < 4; k++) v[k] = x4[idx[k] * 16 + l16];
#pragma unroll
        for (int k = 0; k < 4; k++) {
            const __half2* hp = (const __half2*)&v[k];
#pragma unroll
            for (int j = 0; j < 4; j++) {
                float2 f = __half22float2(hp[j]);
                acc[2 * j]     += f.x;
                acc[2 * j + 1] += f.y;
            }
        }
    }
    for (; c < cnt; c += 4) {
        uint4 v = x4[sorted_src[start + c] * 16 + l16];
        const __half2* hp = (const __half2*)&v;
#pragma unroll
        for (int j = 0; j < 4; j++) {
            float2 f = __half22float2(hp[j]);
            acc[2 * j]     += f.x;
            acc[2 * j + 1] += f.y;
        }
    }
    // combine the 4 groups (same feature columns in all groups)
#pragma unroll
    for (int j = 0; j < 8; j++) {
        acc[j] += __shfl_xor(acc[j], 16);
        acc[j] += __shfl_xor(acc[j], 32);
    }
    if (grp == 0) {
        const float nd = norm_dst[n];
        float4 o0 = make_float4(acc[0] * nd, acc[1] * nd, acc[2] * nd, acc[3] * nd);
        float4 o1 = make_float4(acc[4] * nd, acc[5] * nd, acc[6] * nd, acc[7] * nd);
        float4* op = (float4*)(out + (size_t)n * FEATS + l16 * 8);
        op[0] = o0; op[1] = o1;
    }
}

// ---------------------------------------------------------------------------
// 5) GEMM1: h = fp16(norm_src ⊙ relu(A @ W + b))  (scale + fp16 cast in the
//    epilogue so layer 2 gathers an L2-resident pre-scaled input).
__global__ __launch_bounds__(256) void gemm_relu_scale_kernel(const float* __restrict__ A,
                                                              const float* __restrict__ W,
                                                              const float* __restrict__ bias,
                                                              const float* __restrict__ scale,
                                                              __half* __restrict__ out) {
    __shared__ float As[16 * FEATS];
    int tid = threadIdx.x;
    int nb = blockIdx.x * 16;
    const float4* av = (const float4*)(A + (size_t)nb * FEATS);
    float4* sv = (float4*)As;
    sv[tid]       = av[tid];
    sv[tid + 256] = av[tid + 256];
    __syncthreads();
    int fg = (tid & 31) << 2;
    int r  = tid >> 5;
    const float* a0p = As + r * FEATS;
    const float* a1p = As + (r + 8) * FEATS;
    float4 acc0 = make_float4(0.f, 0.f, 0.f, 0.f);
    float4 acc1 = make_float4(0.f, 0.f, 0.f, 0.f);
#pragma unroll 4
    for (int k = 0; k < FEATS; k++) {
        float a0 = a0p[k];
        float a1 = a1p[k];
        float4 w = *(const float4*)(W + k * FEATS + fg);
        acc0.x = fmaf(a0, w.x, acc0.x); acc0.y = fmaf(a0, w.y, acc0.y);
        acc0.z = fmaf(a0, w.z, acc0.z); acc0.w = fmaf(a0, w.w, acc0.w);
        acc1.x = fmaf(a1, w.x, acc1.x); acc1.y = fmaf(a1, w.y, acc1.y);
        acc1.z = fmaf(a1, w.z, acc1.z); acc1.w = fmaf(a1, w.w, acc1.w);
    }
    float4 bb = *(const float4*)(bias + fg);
    int gn0 = nb + r, gn1 = nb + r + 8;
    float s0 = scale[gn0], s1 = scale[gn1];
    __half2 h00 = __floats2half2_rn(fmaxf(acc0.x + bb.x, 0.f) * s0,
                                    fmaxf(acc0.y + bb.y, 0.f) * s0);
    __half2 h01 = __floats2half2_rn(fmaxf(acc0.z + bb.z, 0.f) * s0,
                                    fmaxf(acc0.w + bb.w, 0.f) * s0);
    __half2 h10 = __floats2half2_rn(fmaxf(acc1.x + bb.x, 0.f) * s1,
                                    fmaxf(acc1.y + bb.y, 0.f) * s1);
    __half2 h11 = __floats2half2_rn(fmaxf(acc1.z + bb.z, 0.f) * s1,
                                    fmaxf(acc1.w + bb.w, 0.f) * s1);
    __half2* o0 = (__half2*)(out + (size_t)gn0 * FEATS + fg);
    __half2* o1 = (__half2*)(out + (size_t)gn1 * FEATS + fg);
    o0[0] = h00; o0[1] = h01;
    o1[0] = h10; o1[1] = h11;
}

// ---------------------------------------------------------------------------
// 6) GEMM2+POOL+FINAL: per node s = relu(A@W2+b2) . Wd ; LDS 64-bin
//    accumulate -> few global atomics; last finished block writes out[].
__global__ __launch_bounds__(256) void gemm_relu_pool_kernel(const float* __restrict__ A,
                                                             const float* __restrict__ W,
                                                             const float* __restrict__ bias,
                                                             const float* __restrict__ Wd,
                                                             const int* __restrict__ gids,
                                                             float* __restrict__ graph_sum,
                                                             const int* __restrict__ graph_cnt,
                                                             const float* __restrict__ bd,
                                                             int* __restrict__ done_counter,
                                                             float* __restrict__ out) {
    __shared__ float As[16 * FEATS];
    __shared__ float bins[N_GRAPHS];
    __shared__ int lastflag;
    int tid = threadIdx.x;
    int nb = blockIdx.x * 16;
    const float4* av = (const float4*)(A + (size_t)nb * FEATS);
    float4* sv = (float4*)As;
    sv[tid]       = av[tid];
    sv[tid + 256] = av[tid + 256];
    if (tid < N_GRAPHS) bins[tid] = 0.f;
    __syncthreads();
    int fg = (tid & 31) << 2;
    int r  = tid >> 5;
    const float* a0p = As + r * FEATS;
    const float* a1p = As + (r + 8) * FEATS;
    float4 acc0 = make_float4(0.f, 0.f, 0.f, 0.f);
    float4 acc1 = make_float4(0.f, 0.f, 0.f, 0.f);
#pragma unroll 4
    for (int k = 0; k < FEATS; k++) {
        float a0 = a0p[k];
        float a1 = a1p[k];
        float4 w = *(const float4*)(W + k * FEATS + fg);
        acc0.x = fmaf(a0, w.x, acc0.x); acc0.y = fmaf(a0, w.y, acc0.y);
        acc0.z = fmaf(a0, w.z, acc0.z); acc0.w = fmaf(a0, w.w, acc0.w);
        acc1.x = fmaf(a1, w.x, acc1.x); acc1.y = fmaf(a1, w.y, acc1.y);
        acc1.z = fmaf(a1, w.z, acc1.z); acc1.w = fmaf(a1, w.w, acc1.w);
    }
    float4 bb = *(const float4*)(bias + fg);
    float4 wd = *(const float4*)(Wd + fg);
    float p0 = fmaxf(acc0.x + bb.x, 0.f) * wd.x + fmaxf(acc0.y + bb.y, 0.f) * wd.y +
               fmaxf(acc0.z + bb.z, 0.f) * wd.z + fmaxf(acc0.w + bb.w, 0.f) * wd.w;
    float p1 = fmaxf(acc1.x + bb.x, 0.f) * wd.x + fmaxf(acc1.y + bb.y, 0.f) * wd.y +
               fmaxf(acc1.z + bb.z, 0.f) * wd.z + fmaxf(acc1.w + bb.w, 0.f) * wd.w;
#pragma unroll
    for (int d = 16; d >= 1; d >>= 1) {
        p0 += __shfl_down(p0, d);
        p1 += __shfl_down(p1, d);
    }
    if ((tid & 31) == 0) {
        int gn0 = nb + r, gn1 = nb + r + 8;
        atomicAdd(&bins[gids[gn0]], p0);
        atomicAdd(&bins[gids[gn1]], p1);
    }
    __syncthreads();
    if (tid < N_GRAPHS) {
        float v = bins[tid];
        if (v != 0.f) atomicAdd(&graph_sum[tid], v);
    }
    // last-block final reduction
    __threadfence();
    __syncthreads();
    if (tid == 0) {
        int done = atomicAdd(done_counter, 1);
        lastflag = (done == gridDim.x - 1);
    }
    __syncthreads();
    if (lastflag && tid < N_GRAPHS) {
        float v = atomicAdd(&graph_sum[tid], 0.f);  // coherent read
        out[tid] = v / fmaxf((float)graph_cnt[tid], 1.f) + bd[0];
    }
}

// ---------------------------------------------------------------------------
extern "C" void kernel_launch(void* const* d_in, const int* in_sizes, int n_in,
                              void* d_out, int out_size, void* d_ws, size_t ws_size,
                              hipStream_t stream) {
    const float* in_feat = (const float*)d_in[0];
    const int*   src     = (const int*)d_in[1];
    const int*   dst     = (const int*)d_in[2];
    const int*   gids    = (const int*)d_in[3];
    const float* W1      = (const float*)d_in[4];
    const float* b1      = (const float*)d_in[5];
    const float* W2      = (const float*)d_in[6];
    const float* b2      = (const float*)d_in[7];
    const float* Wd      = (const float*)d_in[8];
    const float* bd      = (const float*)d_in[9];
    float* out = (float*)d_out;

    char* ws = (char*)d_ws;
    size_t off = 0;
    // --- zero zone (one tiny memset) ---
    int* graph_cnt = (int*)(ws + off); off += N_GRAPHS * 4;
    float* graph_sum = (float*)(ws + off); off += N_GRAPHS * 4;
    int* done_counter = (int*)(ws + off); off += 64;   // padded
    size_t zero_bytes = off;
    // --- non-zeroed scratch ---
    off = align_up(off, 512);
    int* counts  = (int*)(ws + off); off += (size_t)NSLICE * N_NODES * 4;   // 2.56 MB
    off = align_up(off, 512);
    int* scounts = (int*)(ws + off); off += (size_t)NSLICE * N_NODES * 4;   // 2.56 MB
    off = align_up(off, 512);
    int* deg_in  = (int*)(ws + off); off += N_NODES * 4;
    off = align_up(off, 512);
    float* norm_src = (float*)(ws + off); off += N_NODES * 4;
    off = align_up(off, 512);
    float* norm_dst = (float*)(ws + off); off += N_NODES * 4;
    off = align_up(off, 512);
    int* sorted_src = (int*)(ws + off); off += (size_t)N_NODES * CAP * 4 + 4096;  // 6.4 MB
    off = align_up(off, 512);
    __half* xs = (__half*)(ws + off); off += (size_t)N_NODES * FEATS * 2;   // 2.56 MB
    off = align_up(off, 512);
    __half* h  = (__half*)(ws + off); off += (size_t)N_NODES * FEATS * 2;   // 2.56 MB
    off = align_up(off, 512);
    float* agg1 = (float*)(ws + off); off += (size_t)N_NODES * FEATS * 4;   // 5.12 MB
    off = align_up(off, 512);
    float* agg2 = (float*)(ws + off); off += (size_t)N_NODES * FEATS * 4;   // 5.12 MB
    (void)ws_size; // ~27 MB used

    hipMemsetAsync(ws, 0, zero_bytes, stream);

    hist_kernel<<<2 * NSLICE, 256, 0, stream>>>(src, dst, counts, scounts);
    degnorm_base_kernel<<<(N_NODES + 255) / 256, 256, 0, stream>>>(counts, scounts, gids,
                                                                   in_feat, deg_in, norm_src,
                                                                   norm_dst, graph_cnt, xs);
    scatter_kernel<<<NSLICE, 256, 0, stream>>>(src, dst, counts, sorted_src);

    // layer 1 (h is written pre-scaled by norm_src, fp16, for layer 2)
    aggregate_kernel<<<N_NODES / 4, 256, 0, stream>>>(xs, sorted_src, deg_in, norm_dst, agg1);
    gemm_relu_scale_kernel<<<N_NODES / 16, 256, 0, stream>>>(agg1, W1, b1, norm_src, h);

    // layer 2 (+ fused pool/head/final)
    aggregate_kernel<<<N_NODES / 4, 256, 0, stream>>>(h, sorted_src, deg_in, norm_dst, agg2);
    gemm_relu_pool_kernel<<<N_NODES / 16, 256, 0, stream>>>(agg2, W2, b2, Wd, gids,
                                                            graph_sum, graph_cnt, bd,
                                                            done_counter, out);
}

// Round 12
// 184.660 us; speedup vs baseline: 1.1630x; 1.1630x over previous
//
#include <hip/hip_runtime.h>
#include <hip/hip_fp16.h>

#define N_NODES 10000
#define N_EDGES 640000
#define N_GRAPHS 64
#define FEATS 128

#define NSLICE 64
#define EPS (N_EDGES / NSLICE)   // 10000 edges per slice
#define CAP 160                  // padded per-node edge capacity (max in-deg ~112)

static inline size_t align_up(size_t x, size_t a) { return (x + a - 1) & ~(a - 1); }

// ---------------------------------------------------------------------------
// 1) HIST: blocks 0..63 histogram dst-slice b into counts[b][*];
//    blocks 64..127 histogram src-slice (b-64) into scounts[b-64][*].
__global__ __launch_bounds__(256) void hist_kernel(const int* __restrict__ src,
                                                   const int* __restrict__ dst,
                                                   int* __restrict__ counts,
                                                   int* __restrict__ scounts) {
    __shared__ int h[N_NODES];
    const int tid = threadIdx.x;
    const int b = blockIdx.x;
    const bool is_dst = (b < NSLICE);
    const int slice = is_dst ? b : b - NSLICE;
    const int* col = is_dst ? dst : src;
    int* outp = (is_dst ? counts : scounts) + slice * N_NODES;

    for (int i = tid; i < N_NODES; i += 256) h[i] = 0;
    __syncthreads();
    const int4* c4 = (const int4*)(col + slice * EPS);
    for (int i = tid; i < EPS / 4; i += 256) {
        int4 v = c4[i];
        atomicAdd(&h[v.x], 1);
        atomicAdd(&h[v.y], 1);
        atomicAdd(&h[v.z], 1);
        atomicAdd(&h[v.w], 1);
    }
    __syncthreads();
    for (int i = tid; i < N_NODES; i += 256) outp[i] = h[i];
}

// ---------------------------------------------------------------------------
// 2) DEGNORM+BASE+PRESCALE: per node n, scan counts along slices in-place
//    into write bases seeded with n*CAP; deg_in / norms / graph counts; then
//    the block prescales its own 256 nodes: xs = fp16(in_feat * norm_src).
__global__ __launch_bounds__(256) void degnorm_base_kernel(int* __restrict__ counts,
                                                           const int* __restrict__ scounts,
                                                           const int* __restrict__ gids,
                                                           const float* __restrict__ in_feat,
                                                           int* __restrict__ deg_in,
                                                           float* __restrict__ norm_src,
                                                           float* __restrict__ norm_dst,
                                                           int* __restrict__ graph_cnt,
                                                           __half* __restrict__ xs) {
    __shared__ int gcnt[N_GRAPHS];
    __shared__ float ns_l[256];
    const int tid = threadIdx.x;
    const int base_n = blockIdx.x * 256;
    if (tid < N_GRAPHS) gcnt[tid] = 0;
    __syncthreads();
    int n = base_n + tid;
    float ns = 0.f;
    if (n < N_NODES) {
        int run = n * CAP;
        for (int s = 0; s < NSLICE; s++) {
            int c = counts[s * N_NODES + n];
            counts[s * N_NODES + n] = run;
            run += c;
        }
        int di = run - n * CAP;
        int dou = 0;
        for (int s = 0; s < NSLICE; s++) dou += scounts[s * N_NODES + n];
        deg_in[n] = di;
        norm_dst[n] = rsqrtf((float)(di < 1 ? 1 : di));
        ns = rsqrtf((float)(dou < 1 ? 1 : dou));
        norm_src[n] = ns;
        atomicAdd(&gcnt[gids[n]], 1);
    }
    ns_l[tid] = ns;
    __syncthreads();
    if (tid < N_GRAPHS && gcnt[tid]) atomicAdd(&graph_cnt[tid], gcnt[tid]);

    // prescale this block's 256 nodes (coalesced: 32 consecutive lanes per node)
    const float4* inf4 = (const float4*)in_feat;
    for (int i = tid; i < 256 * 32; i += 256) {
        int nloc = i >> 5;
        int n2 = base_n + nloc;
        if (n2 < N_NODES) {
            float4 v = inf4[(size_t)n2 * 32 + (i & 31)];
            float s = ns_l[nloc];
            __half2 h0 = __floats2half2_rn(v.x * s, v.y * s);
            __half2 h1 = __floats2half2_rn(v.z * s, v.w * s);
            __half2* o = (__half2*)(xs + (size_t)n2 * FEATS + (i & 31) * 4);
            o[0] = h0; o[1] = h1;
        }
    }
}

// ---------------------------------------------------------------------------
// 3) SCATTER: block s places its EPS edges via LDS cursors into the padded CSR.
__global__ __launch_bounds__(256) void scatter_kernel(const int* __restrict__ src,
                                                      const int* __restrict__ dst,
                                                      const int* __restrict__ base,
                                                      int* __restrict__ sorted_src) {
    __shared__ int cur[N_NODES];
    const int tid = threadIdx.x;
    const int s = blockIdx.x;
    for (int i = tid; i < N_NODES; i += 256) cur[i] = base[s * N_NODES + i];
    __syncthreads();
    const int4* s4 = (const int4*)(src + s * EPS);
    const int4* d4 = (const int4*)(dst + s * EPS);
    for (int i = tid; i < EPS / 4; i += 256) {
        int4 sv = s4[i];
        int4 dv = d4[i];
        int p;
        p = atomicAdd(&cur[dv.x], 1); sorted_src[p] = sv.x;
        p = atomicAdd(&cur[dv.y], 1); sorted_src[p] = sv.y;
        p = atomicAdd(&cur[dv.z], 1); sorted_src[p] = sv.z;
        p = atomicAdd(&cur[dv.w], 1); sorted_src[p] = sv.w;
    }
}

// ---------------------------------------------------------------------------
// 4) AGGREGATE (fp16 in, fp32 out): one wave per dst node. Quarter-wave
//    (16 lanes x 16 B) fetches one 256 B fp16 row per instr -> 4 edges per
//    wave instruction; unroll x4 keeps 16 rows (4 KB) in flight per wave.
__global__ __launch_bounds__(256) void aggregate_kernel(const __half* __restrict__ X,
                                                        const int* __restrict__ sorted_src,
                                                        const int* __restrict__ deg_in,
                                                        const float* __restrict__ norm_dst,
                                                        float* __restrict__ out) {
    const int tid = threadIdx.x;
    const int wave = tid >> 6, lane = tid & 63;
    const int grp = lane >> 4, l16 = lane & 15;
    const int n = blockIdx.x * 4 + wave;
    const int start = n * CAP;
    const int cnt = deg_in[n];
    const uint4* __restrict__ x4 = (const uint4*)X;  // row = 16 uint4 (256 B)
    float acc[8] = {0.f, 0.f, 0.f, 0.f, 0.f, 0.f, 0.f, 0.f};

    // group `grp` handles edges congruent to `grp` (mod 4)
    int c = grp;
    for (; c + 12 < cnt; c += 16) {
        int idx[4];
#pragma unroll
        for (int k = 0; k < 4; k++) idx[k] = sorted_src[start + c + 4 * k];
        uint4 v[4];
#pragma unroll
        for (int k = 0; k < 4; k++) v[k] = x4[idx[k] * 16 + l16];
#pragma unroll
        for (int k = 0; k < 4; k++) {
            const __half2* hp = (const __half2*)&v[k];
#pragma unroll
            for (int j = 0; j < 4; j++) {
                float2 f = __half22float2(hp[j]);
                acc[2 * j]     += f.x;
                acc[2 * j + 1] += f.y;
            }
        }
    }
    for (; c < cnt; c += 4) {
        uint4 v = x4[sorted_src[start + c] * 16 + l16];
        const __half2* hp = (const __half2*)&v;
#pragma unroll
        for (int j = 0; j < 4; j++) {
            float2 f = __half22float2(hp[j]);
            acc[2 * j]     += f.x;
            acc[2 * j + 1] += f.y;
        }
    }
    // combine the 4 groups (same feature columns in all groups)
#pragma unroll
    for (int j = 0; j < 8; j++) {
        acc[j] += __shfl_xor(acc[j], 16);
        acc[j] += __shfl_xor(acc[j], 32);
    }
    if (grp == 0) {
        const float nd = norm_dst[n];
        float4 o0 = make_float4(acc[0] * nd, acc[1] * nd, acc[2] * nd, acc[3] * nd);
        float4 o1 = make_float4(acc[4] * nd, acc[5] * nd, acc[6] * nd, acc[7] * nd);
        float4* op = (float4*)(out + (size_t)n * FEATS + l16 * 8);
        op[0] = o0; op[1] = o1;
    }
}

// ---------------------------------------------------------------------------
// 5) GEMM1: h = fp16(norm_src ⊙ relu(A @ W + b))  (scale + fp16 cast in the
//    epilogue so layer 2 gathers an L2-resident pre-scaled input).
__global__ __launch_bounds__(256) void gemm_relu_scale_kernel(const float* __restrict__ A,
                                                              const float* __restrict__ W,
                                                              const float* __restrict__ bias,
                                                              const float* __restrict__ scale,
                                                              __half* __restrict__ out) {
    __shared__ float As[16 * FEATS];
    int tid = threadIdx.x;
    int nb = blockIdx.x * 16;
    const float4* av = (const float4*)(A + (size_t)nb * FEATS);
    float4* sv = (float4*)As;
    sv[tid]       = av[tid];
    sv[tid + 256] = av[tid + 256];
    __syncthreads();
    int fg = (tid & 31) << 2;
    int r  = tid >> 5;
    const float* a0p = As + r * FEATS;
    const float* a1p = As + (r + 8) * FEATS;
    float4 acc0 = make_float4(0.f, 0.f, 0.f, 0.f);
    float4 acc1 = make_float4(0.f, 0.f, 0.f, 0.f);
#pragma unroll 4
    for (int k = 0; k < FEATS; k++) {
        float a0 = a0p[k];
        float a1 = a1p[k];
        float4 w = *(const float4*)(W + k * FEATS + fg);
        acc0.x = fmaf(a0, w.x, acc0.x); acc0.y = fmaf(a0, w.y, acc0.y);
        acc0.z = fmaf(a0, w.z, acc0.z); acc0.w = fmaf(a0, w.w, acc0.w);
        acc1.x = fmaf(a1, w.x, acc1.x); acc1.y = fmaf(a1, w.y, acc1.y);
        acc1.z = fmaf(a1, w.z, acc1.z); acc1.w = fmaf(a1, w.w, acc1.w);
    }
    float4 bb = *(const float4*)(bias + fg);
    int gn0 = nb + r, gn1 = nb + r + 8;
    float s0 = scale[gn0], s1 = scale[gn1];
    __half2 h00 = __floats2half2_rn(fmaxf(acc0.x + bb.x, 0.f) * s0,
                                    fmaxf(acc0.y + bb.y, 0.f) * s0);
    __half2 h01 = __floats2half2_rn(fmaxf(acc0.z + bb.z, 0.f) * s0,
                                    fmaxf(acc0.w + bb.w, 0.f) * s0);
    __half2 h10 = __floats2half2_rn(fmaxf(acc1.x + bb.x, 0.f) * s1,
                                    fmaxf(acc1.y + bb.y, 0.f) * s1);
    __half2 h11 = __floats2half2_rn(fmaxf(acc1.z + bb.z, 0.f) * s1,
                                    fmaxf(acc1.w + bb.w, 0.f) * s1);
    __half2* o0 = (__half2*)(out + (size_t)gn0 * FEATS + fg);
    __half2* o1 = (__half2*)(out + (size_t)gn1 * FEATS + fg);
    o0[0] = h00; o0[1] = h01;
    o1[0] = h10; o1[1] = h11;
}

// ---------------------------------------------------------------------------
// 6) GEMM2+POOL: per node s = relu(A@W2+b2) . Wd ; LDS 64-bin accumulate,
//    then few global atomics per block. NO device-scope fence here — the
//    R11 last-block-final pattern's per-block __threadfence cost ~45 µs.
__global__ __launch_bounds__(256) void gemm_relu_pool_kernel(const float* __restrict__ A,
                                                             const float* __restrict__ W,
                                                             const float* __restrict__ bias,
                                                             const float* __restrict__ Wd,
                                                             const int* __restrict__ gids,
                                                             float* __restrict__ graph_sum) {
    __shared__ float As[16 * FEATS];
    __shared__ float bins[N_GRAPHS];
    int tid = threadIdx.x;
    int nb = blockIdx.x * 16;
    const float4* av = (const float4*)(A + (size_t)nb * FEATS);
    float4* sv = (float4*)As;
    sv[tid]       = av[tid];
    sv[tid + 256] = av[tid + 256];
    if (tid < N_GRAPHS) bins[tid] = 0.f;
    __syncthreads();
    int fg = (tid & 31) << 2;
    int r  = tid >> 5;
    const float* a0p = As + r * FEATS;
    const float* a1p = As + (r + 8) * FEATS;
    float4 acc0 = make_float4(0.f, 0.f, 0.f, 0.f);
    float4 acc1 = make_float4(0.f, 0.f, 0.f, 0.f);
#pragma unroll 4
    for (int k = 0; k < FEATS; k++) {
        float a0 = a0p[k];
        float a1 = a1p[k];
        float4 w = *(const float4*)(W + k * FEATS + fg);
        acc0.x = fmaf(a0, w.x, acc0.x); acc0.y = fmaf(a0, w.y, acc0.y);
        acc0.z = fmaf(a0, w.z, acc0.z); acc0.w = fmaf(a0, w.w, acc0.w);
        acc1.x = fmaf(a1, w.x, acc1.x); acc1.y = fmaf(a1, w.y, acc1.y);
        acc1.z = fmaf(a1, w.z, acc1.z); acc1.w = fmaf(a1, w.w, acc1.w);
    }
    float4 bb = *(const float4*)(bias + fg);
    float4 wd = *(const float4*)(Wd + fg);
    float p0 = fmaxf(acc0.x + bb.x, 0.f) * wd.x + fmaxf(acc0.y + bb.y, 0.f) * wd.y +
               fmaxf(acc0.z + bb.z, 0.f) * wd.z + fmaxf(acc0.w + bb.w, 0.f) * wd.w;
    float p1 = fmaxf(acc1.x + bb.x, 0.f) * wd.x + fmaxf(acc1.y + bb.y, 0.f) * wd.y +
               fmaxf(acc1.z + bb.z, 0.f) * wd.z + fmaxf(acc1.w + bb.w, 0.f) * wd.w;
#pragma unroll
    for (int d = 16; d >= 1; d >>= 1) {
        p0 += __shfl_down(p0, d);
        p1 += __shfl_down(p1, d);
    }
    if ((tid & 31) == 0) {
        int gn0 = nb + r, gn1 = nb + r + 8;
        atomicAdd(&bins[gids[gn0]], p0);
        atomicAdd(&bins[gids[gn1]], p1);
    }
    __syncthreads();
    if (tid < N_GRAPHS) {
        float v = bins[tid];
        if (v != 0.f) atomicAdd(&graph_sum[tid], v);
    }
}

// ---------------------------------------------------------------------------
// 7) final: out[g] = graph_sum[g] / max(cnt,1) + bd
__global__ __launch_bounds__(64) void final_kernel(const float* __restrict__ graph_sum,
                                                   const int* __restrict__ graph_cnt,
                                                   const float* __restrict__ bd,
                                                   float* __restrict__ out) {
    int g = threadIdx.x;
    if (g < N_GRAPHS) {
        out[g] = graph_sum[g] / fmaxf((float)graph_cnt[g], 1.f) + bd[0];
    }
}

// ---------------------------------------------------------------------------
extern "C" void kernel_launch(void* const* d_in, const int* in_sizes, int n_in,
                              void* d_out, int out_size, void* d_ws, size_t ws_size,
                              hipStream_t stream) {
    const float* in_feat = (const float*)d_in[0];
    const int*   src     = (const int*)d_in[1];
    const int*   dst     = (const int*)d_in[2];
    const int*   gids    = (const int*)d_in[3];
    const float* W1      = (const float*)d_in[4];
    const float* b1      = (const float*)d_in[5];
    const float* W2      = (const float*)d_in[6];
    const float* b2      = (const float*)d_in[7];
    const float* Wd      = (const float*)d_in[8];
    const float* bd      = (const float*)d_in[9];
    float* out = (float*)d_out;

    char* ws = (char*)d_ws;
    size_t off = 0;
    // --- zero zone (one tiny memset) ---
    int* graph_cnt = (int*)(ws + off); off += N_GRAPHS * 4;
    float* graph_sum = (float*)(ws + off); off += N_GRAPHS * 4;
    size_t zero_bytes = off;
    // --- non-zeroed scratch ---
    off = align_up(off, 512);
    int* counts  = (int*)(ws + off); off += (size_t)NSLICE * N_NODES * 4;   // 2.56 MB
    off = align_up(off, 512);
    int* scounts = (int*)(ws + off); off += (size_t)NSLICE * N_NODES * 4;   // 2.56 MB
    off = align_up(off, 512);
    int* deg_in  = (int*)(ws + off); off += N_NODES * 4;
    off = align_up(off, 512);
    float* norm_src = (float*)(ws + off); off += N_NODES * 4;
    off = align_up(off, 512);
    float* norm_dst = (float*)(ws + off); off += N_NODES * 4;
    off = align_up(off, 512);
    int* sorted_src = (int*)(ws + off); off += (size_t)N_NODES * CAP * 4 + 4096;  // 6.4 MB
    off = align_up(off, 512);
    __half* xs = (__half*)(ws + off); off += (size_t)N_NODES * FEATS * 2;   // 2.56 MB
    off = align_up(off, 512);
    __half* h  = (__half*)(ws + off); off += (size_t)N_NODES * FEATS * 2;   // 2.56 MB
    off = align_up(off, 512);
    float* agg1 = (float*)(ws + off); off += (size_t)N_NODES * FEATS * 4;   // 5.12 MB
    off = align_up(off, 512);
    float* agg2 = (float*)(ws + off); off += (size_t)N_NODES * FEATS * 4;   // 5.12 MB
    (void)ws_size; // ~27 MB used

    hipMemsetAsync(ws, 0, zero_bytes, stream);

    hist_kernel<<<2 * NSLICE, 256, 0, stream>>>(src, dst, counts, scounts);
    degnorm_base_kernel<<<(N_NODES + 255) / 256, 256, 0, stream>>>(counts, scounts, gids,
                                                                   in_feat, deg_in, norm_src,
                                                                   norm_dst, graph_cnt, xs);
    scatter_kernel<<<NSLICE, 256, 0, stream>>>(src, dst, counts, sorted_src);

    // layer 1 (h is written pre-scaled by norm_src, fp16, for layer 2)
    aggregate_kernel<<<N_NODES / 4, 256, 0, stream>>>(xs, sorted_src, deg_in, norm_dst, agg1);
    gemm_relu_scale_kernel<<<N_NODES / 16, 256, 0, stream>>>(agg1, W1, b1, norm_src, h);

    // layer 2 (+ fused pool)
    aggregate_kernel<<<N_NODES / 4, 256, 0, stream>>>(h, sorted_src, deg_in, norm_dst, agg2);
    gemm_relu_pool_kernel<<<N_NODES / 16, 256, 0, stream>>>(agg2, W2, b2, Wd, gids, graph_sum);

    final_kernel<<<1, 64, 0, stream>>>(graph_sum, graph_cnt, bd, out);
}

// Round 13
// 170.443 us; speedup vs baseline: 1.2600x; 1.0834x over previous
//
#include <hip/hip_runtime.h>
#include <hip/hip_fp16.h>

#define N_NODES 10000
#define N_EDGES 640000
#define N_GRAPHS 64
#define FEATS 128

#define NSLICE 64
#define EPS (N_EDGES / NSLICE)   // 10000 edges per slice
#define CAP 160                  // padded per-node edge capacity (max in-deg ~112)
#define PRE_BLOCKS 1250          // 320000 float4 / 256

static inline size_t align_up(size_t x, size_t a) { return (x + a - 1) & ~(a - 1); }

// ---------------------------------------------------------------------------
// 1) HIST: blocks 0..63 histogram dst-slice b into counts[b][*];
//    blocks 64..127 histogram src-slice (b-64) into scounts[b-64][*].
//    Block 0 also zero-inits graph_cnt/graph_sum (replaces the memset dispatch).
__global__ __launch_bounds__(256) void hist_kernel(const int* __restrict__ src,
                                                   const int* __restrict__ dst,
                                                   int* __restrict__ counts,
                                                   int* __restrict__ scounts,
                                                   int* __restrict__ graph_cnt,
                                                   float* __restrict__ graph_sum) {
    __shared__ int h[N_NODES];
    const int tid = threadIdx.x;
    const int b = blockIdx.x;
    if (b == 0 && tid < 2 * N_GRAPHS) {
        if (tid < N_GRAPHS) graph_cnt[tid] = 0;
        else                graph_sum[tid - N_GRAPHS] = 0.f;
    }
    const bool is_dst = (b < NSLICE);
    const int slice = is_dst ? b : b - NSLICE;
    const int* col = is_dst ? dst : src;
    int* outp = (is_dst ? counts : scounts) + slice * N_NODES;

    for (int i = tid; i < N_NODES; i += 256) h[i] = 0;
    __syncthreads();
    const int4* c4 = (const int4*)(col + slice * EPS);
    for (int i = tid; i < EPS / 4; i += 256) {
        int4 v = c4[i];
        atomicAdd(&h[v.x], 1);
        atomicAdd(&h[v.y], 1);
        atomicAdd(&h[v.z], 1);
        atomicAdd(&h[v.w], 1);
    }
    __syncthreads();
    for (int i = tid; i < N_NODES; i += 256) outp[i] = h[i];
}

// ---------------------------------------------------------------------------
// 2) DEGNORM+BASE: per node n, scan counts along slices in-place into write
//    bases seeded with n*CAP; deg_in / norms / graph counts in same pass.
//    (Prescale deliberately NOT fused here: 40 blocks would throttle the
//    12.5 MB stream — R12 lesson.)
__global__ __launch_bounds__(256) void degnorm_base_kernel(int* __restrict__ counts,
                                                           const int* __restrict__ scounts,
                                                           const int* __restrict__ gids,
                                                           int* __restrict__ deg_in,
                                                           float* __restrict__ norm_src,
                                                           float* __restrict__ norm_dst,
                                                           int* __restrict__ graph_cnt) {
    __shared__ int gcnt[N_GRAPHS];
    const int tid = threadIdx.x;
    if (tid < N_GRAPHS) gcnt[tid] = 0;
    __syncthreads();
    int n = blockIdx.x * 256 + tid;
    if (n < N_NODES) {
        int run = n * CAP;
        for (int s = 0; s < NSLICE; s++) {
            int c = counts[s * N_NODES + n];
            counts[s * N_NODES + n] = run;
            run += c;
        }
        int di = run - n * CAP;
        int dou = 0;
        for (int s = 0; s < NSLICE; s++) dou += scounts[s * N_NODES + n];
        deg_in[n] = di;
        norm_dst[n] = rsqrtf((float)(di < 1 ? 1 : di));
        norm_src[n] = rsqrtf((float)(dou < 1 ? 1 : dou));
        atomicAdd(&gcnt[gids[n]], 1);
    }
    __syncthreads();
    if (tid < N_GRAPHS && gcnt[tid]) atomicAdd(&graph_cnt[tid], gcnt[tid]);
}

// ---------------------------------------------------------------------------
// 3) SCATTER+PRESCALE (independent work, one dispatch):
//    blocks 0..63: place EPS edges via LDS cursors into the padded CSR;
//    blocks 64..1313: xs = fp16(in_feat * norm_src) at full streaming width.
__global__ __launch_bounds__(256) void scatter_prescale_kernel(const int* __restrict__ src,
                                                               const int* __restrict__ dst,
                                                               const int* __restrict__ base,
                                                               int* __restrict__ sorted_src,
                                                               const float* __restrict__ in_feat,
                                                               const float* __restrict__ norm_src,
                                                               __half* __restrict__ xs) {
    const int tid = threadIdx.x;
    if (blockIdx.x < NSLICE) {
        __shared__ int cur[N_NODES];
        const int s = blockIdx.x;
        for (int i = tid; i < N_NODES; i += 256) cur[i] = base[s * N_NODES + i];
        __syncthreads();
        const int4* s4 = (const int4*)(src + s * EPS);
        const int4* d4 = (const int4*)(dst + s * EPS);
        for (int i = tid; i < EPS / 4; i += 256) {
            int4 sv = s4[i];
            int4 dv = d4[i];
            int p;
            p = atomicAdd(&cur[dv.x], 1); sorted_src[p] = sv.x;
            p = atomicAdd(&cur[dv.y], 1); sorted_src[p] = sv.y;
            p = atomicAdd(&cur[dv.z], 1); sorted_src[p] = sv.z;
            p = atomicAdd(&cur[dv.w], 1); sorted_src[p] = sv.w;
        }
    } else {
        int i = (blockIdx.x - NSLICE) * 256 + tid;  // over 320000 float4
        if (i < N_NODES * (FEATS / 4)) {
            int n = i >> 5;
            float4 v = ((const float4*)in_feat)[i];
            float s = norm_src[n];
            __half2 h0 = __floats2half2_rn(v.x * s, v.y * s);
            __half2 h1 = __floats2half2_rn(v.z * s, v.w * s);
            __half2* o = (__half2*)(xs + (size_t)i * 4);
            o[0] = h0; o[1] = h1;
        }
    }
}

// ---------------------------------------------------------------------------
// 4) AGGREGATE (fp16 in, fp32 out): one wave per dst node. Quarter-wave
//    (16 lanes x 16 B) fetches one 256 B fp16 row per instr -> 4 edges per
//    wave instruction; unroll x4 keeps 16 rows (4 KB) in flight per wave.
__global__ __launch_bounds__(256) void aggregate_kernel(const __half* __restrict__ X,
                                                        const int* __restrict__ sorted_src,
                                                        const int* __restrict__ deg_in,
                                                        const float* __restrict__ norm_dst,
                                                        float* __restrict__ out) {
    const int tid = threadIdx.x;
    const int wave = tid >> 6, lane = tid & 63;
    const int grp = lane >> 4, l16 = lane & 15;
    const int n = blockIdx.x * 4 + wave;
    const int start = n * CAP;
    const int cnt = deg_in[n];
    const uint4* __restrict__ x4 = (const uint4*)X;  // row = 16 uint4 (256 B)
    float acc[8] = {0.f, 0.f, 0.f, 0.f, 0.f, 0.f, 0.f, 0.f};

    // group `grp` handles edges congruent to `grp` (mod 4)
    int c = grp;
    for (; c + 12 < cnt; c += 16) {
        int idx[4];
#pragma unroll
        for (int k = 0; k < 4; k++) idx[k] = sorted_src[start + c + 4 * k];
        uint4 v[4];
#pragma unroll
        for (int k = 0; k < 4; k++) v[k] = x4[idx[k] * 16 + l16];
#pragma unroll
        for (int k = 0; k < 4; k++) {
            const __half2* hp = (const __half2*)&v[k];
#pragma unroll
            for (int j = 0; j < 4; j++) {
                float2 f = __half22float2(hp[j]);
                acc[2 * j]     += f.x;
                acc[2 * j + 1] += f.y;
            }
        }
    }
    for (; c < cnt; c += 4) {
        uint4 v = x4[sorted_src[start + c] * 16 + l16];
        const __half2* hp = (const __half2*)&v;
#pragma unroll
        for (int j = 0; j < 4; j++) {
            float2 f = __half22float2(hp[j]);
            acc[2 * j]     += f.x;
            acc[2 * j + 1] += f.y;
        }
    }
    // combine the 4 groups (same feature columns in all groups)
#pragma unroll
    for (int j = 0; j < 8; j++) {
        acc[j] += __shfl_xor(acc[j], 16);
        acc[j] += __shfl_xor(acc[j], 32);
    }
    if (grp == 0) {
        const float nd = norm_dst[n];
        float4 o0 = make_float4(acc[0] * nd, acc[1] * nd, acc[2] * nd, acc[3] * nd);
        float4 o1 = make_float4(acc[4] * nd, acc[5] * nd, acc[6] * nd, acc[7] * nd);
        float4* op = (float4*)(out + (size_t)n * FEATS + l16 * 8);
        op[0] = o0; op[1] = o1;
    }
}

// ---------------------------------------------------------------------------
// 5) GEMM1: h = fp16(norm_src ⊙ relu(A @ W + b))
__global__ __launch_bounds__(256) void gemm_relu_scale_kernel(const float* __restrict__ A,
                                                              const float* __restrict__ W,
                                                              const float* __restrict__ bias,
                                                              const float* __restrict__ scale,
                                                              __half* __restrict__ out) {
    __shared__ float As[16 * FEATS];
    int tid = threadIdx.x;
    int nb = blockIdx.x * 16;
    const float4* av = (const float4*)(A + (size_t)nb * FEATS);
    float4* sv = (float4*)As;
    sv[tid]       = av[tid];
    sv[tid + 256] = av[tid + 256];
    __syncthreads();
    int fg = (tid & 31) << 2;
    int r  = tid >> 5;
    const float* a0p = As + r * FEATS;
    const float* a1p = As + (r + 8) * FEATS;
    float4 acc0 = make_float4(0.f, 0.f, 0.f, 0.f);
    float4 acc1 = make_float4(0.f, 0.f, 0.f, 0.f);
#pragma unroll 4
    for (int k = 0; k < FEATS; k++) {
        float a0 = a0p[k];
        float a1 = a1p[k];
        float4 w = *(const float4*)(W + k * FEATS + fg);
        acc0.x = fmaf(a0, w.x, acc0.x); acc0.y = fmaf(a0, w.y, acc0.y);
        acc0.z = fmaf(a0, w.z, acc0.z); acc0.w = fmaf(a0, w.w, acc0.w);
        acc1.x = fmaf(a1, w.x, acc1.x); acc1.y = fmaf(a1, w.y, acc1.y);
        acc1.z = fmaf(a1, w.z, acc1.z); acc1.w = fmaf(a1, w.w, acc1.w);
    }
    float4 bb = *(const float4*)(bias + fg);
    int gn0 = nb + r, gn1 = nb + r + 8;
    float s0 = scale[gn0], s1 = scale[gn1];
    __half2 h00 = __floats2half2_rn(fmaxf(acc0.x + bb.x, 0.f) * s0,
                                    fmaxf(acc0.y + bb.y, 0.f) * s0);
    __half2 h01 = __floats2half2_rn(fmaxf(acc0.z + bb.z, 0.f) * s0,
                                    fmaxf(acc0.w + bb.w, 0.f) * s0);
    __half2 h10 = __floats2half2_rn(fmaxf(acc1.x + bb.x, 0.f) * s1,
                                    fmaxf(acc1.y + bb.y, 0.f) * s1);
    __half2 h11 = __floats2half2_rn(fmaxf(acc1.z + bb.z, 0.f) * s1,
                                    fmaxf(acc1.w + bb.w, 0.f) * s1);
    __half2* o0 = (__half2*)(out + (size_t)gn0 * FEATS + fg);
    __half2* o1 = (__half2*)(out + (size_t)gn1 * FEATS + fg);
    o0[0] = h00; o0[1] = h01;
    o1[0] = h10; o1[1] = h11;
}

// ---------------------------------------------------------------------------
// 6) GEMM2+POOL: per node s = relu(A@W2+b2) . Wd ; LDS 64-bin accumulate,
//    then few global atomics per block. No device-scope fence (R11 lesson).
__global__ __launch_bounds__(256) void gemm_relu_pool_kernel(const float* __restrict__ A,
                                                             const float* __restrict__ W,
                                                             const float* __restrict__ bias,
                                                             const float* __restrict__ Wd,
                                                             const int* __restrict__ gids,
                                                             float* __restrict__ graph_sum) {
    __shared__ float As[16 * FEATS];
    __shared__ float bins[N_GRAPHS];
    int tid = threadIdx.x;
    int nb = blockIdx.x * 16;
    const float4* av = (const float4*)(A + (size_t)nb * FEATS);
    float4* sv = (float4*)As;
    sv[tid]       = av[tid];
    sv[tid + 256] = av[tid + 256];
    if (tid < N_GRAPHS) bins[tid] = 0.f;
    __syncthreads();
    int fg = (tid & 31) << 2;
    int r  = tid >> 5;
    const float* a0p = As + r * FEATS;
    const float* a1p = As + (r + 8) * FEATS;
    float4 acc0 = make_float4(0.f, 0.f, 0.f, 0.f);
    float4 acc1 = make_float4(0.f, 0.f, 0.f, 0.f);
#pragma unroll 4
    for (int k = 0; k < FEATS; k++) {
        float a0 = a0p[k];
        float a1 = a1p[k];
        float4 w = *(const float4*)(W + k * FEATS + fg);
        acc0.x = fmaf(a0, w.x, acc0.x); acc0.y = fmaf(a0, w.y, acc0.y);
        acc0.z = fmaf(a0, w.z, acc0.z); acc0.w = fmaf(a0, w.w, acc0.w);
        acc1.x = fmaf(a1, w.x, acc1.x); acc1.y = fmaf(a1, w.y, acc1.y);
        acc1.z = fmaf(a1, w.z, acc1.z); acc1.w = fmaf(a1, w.w, acc1.w);
    }
    float4 bb = *(const float4*)(bias + fg);
    float4 wd = *(const float4*)(Wd + fg);
    float p0 = fmaxf(acc0.x + bb.x, 0.f) * wd.x + fmaxf(acc0.y + bb.y, 0.f) * wd.y +
               fmaxf(acc0.z + bb.z, 0.f) * wd.z + fmaxf(acc0.w + bb.w, 0.f) * wd.w;
    float p1 = fmaxf(acc1.x + bb.x, 0.f) * wd.x + fmaxf(acc1.y + bb.y, 0.f) * wd.y +
               fmaxf(acc1.z + bb.z, 0.f) * wd.z + fmaxf(acc1.w + bb.w, 0.f) * wd.w;
#pragma unroll
    for (int d = 16; d >= 1; d >>= 1) {
        p0 += __shfl_down(p0, d);
        p1 += __shfl_down(p1, d);
    }
    if ((tid & 31) == 0) {
        int gn0 = nb + r, gn1 = nb + r + 8;
        atomicAdd(&bins[gids[gn0]], p0);
        atomicAdd(&bins[gids[gn1]], p1);
    }
    __syncthreads();
    if (tid < N_GRAPHS) {
        float v = bins[tid];
        if (v != 0.f) atomicAdd(&graph_sum[tid], v);
    }
}

// ---------------------------------------------------------------------------
// 7) final: out[g] = graph_sum[g] / max(cnt,1) + bd
__global__ __launch_bounds__(64) void final_kernel(const float* __restrict__ graph_sum,
                                                   const int* __restrict__ graph_cnt,
                                                   const float* __restrict__ bd,
                                                   float* __restrict__ out) {
    int g = threadIdx.x;
    if (g < N_GRAPHS) {
        out[g] = graph_sum[g] / fmaxf((float)graph_cnt[g], 1.f) + bd[0];
    }
}

// ---------------------------------------------------------------------------
extern "C" void kernel_launch(void* const* d_in, const int* in_sizes, int n_in,
                              void* d_out, int out_size, void* d_ws, size_t ws_size,
                              hipStream_t stream) {
    const float* in_feat = (const float*)d_in[0];
    const int*   src     = (const int*)d_in[1];
    const int*   dst     = (const int*)d_in[2];
    const int*   gids    = (const int*)d_in[3];
    const float* W1      = (const float*)d_in[4];
    const float* b1      = (const float*)d_in[5];
    const float* W2      = (const float*)d_in[6];
    const float* b2      = (const float*)d_in[7];
    const float* Wd      = (const float*)d_in[8];
    const float* bd      = (const float*)d_in[9];
    float* out = (float*)d_out;

    char* ws = (char*)d_ws;
    size_t off = 0;
    int* graph_cnt = (int*)(ws + off); off += N_GRAPHS * 4;
    float* graph_sum = (float*)(ws + off); off += N_GRAPHS * 4;
    off = align_up(off, 512);
    int* counts  = (int*)(ws + off); off += (size_t)NSLICE * N_NODES * 4;   // 2.56 MB
    off = align_up(off, 512);
    int* scounts = (int*)(ws + off); off += (size_t)NSLICE * N_NODES * 4;   // 2.56 MB
    off = align_up(off, 512);
    int* deg_in  = (int*)(ws + off); off += N_NODES * 4;
    off = align_up(off, 512);
    float* norm_src = (float*)(ws + off); off += N_NODES * 4;
    off = align_up(off, 512);
    float* norm_dst = (float*)(ws + off); off += N_NODES * 4;
    off = align_up(off, 512);
    int* sorted_src = (int*)(ws + off); off += (size_t)N_NODES * CAP * 4 + 4096;  // 6.4 MB
    off = align_up(off, 512);
    __half* xs = (__half*)(ws + off); off += (size_t)N_NODES * FEATS * 2;   // 2.56 MB
    off = align_up(off, 512);
    __half* h  = (__half*)(ws + off); off += (size_t)N_NODES * FEATS * 2;   // 2.56 MB
    off = align_up(off, 512);
    float* agg1 = (float*)(ws + off); off += (size_t)N_NODES * FEATS * 4;   // 5.12 MB
    off = align_up(off, 512);
    float* agg2 = (float*)(ws + off); off += (size_t)N_NODES * FEATS * 4;   // 5.12 MB
    (void)ws_size; // ~27 MB used

    hist_kernel<<<2 * NSLICE, 256, 0, stream>>>(src, dst, counts, scounts,
                                                graph_cnt, graph_sum);
    degnorm_base_kernel<<<(N_NODES + 255) / 256, 256, 0, stream>>>(counts, scounts, gids,
                                                                   deg_in, norm_src,
                                                                   norm_dst, graph_cnt);
    scatter_prescale_kernel<<<NSLICE + PRE_BLOCKS, 256, 0, stream>>>(src, dst, counts,
                                                                     sorted_src, in_feat,
                                                                     norm_src, xs);

    // layer 1 (h is written pre-scaled by norm_src, fp16, for layer 2)
    aggregate_kernel<<<N_NODES / 4, 256, 0, stream>>>(xs, sorted_src, deg_in, norm_dst, agg1);
    gemm_relu_scale_kernel<<<N_NODES / 16, 256, 0, stream>>>(agg1, W1, b1, norm_src, h);

    // layer 2 (+ fused pool)
    aggregate_kernel<<<N_NODES / 4, 256, 0, stream>>>(h, sorted_src, deg_in, norm_dst, agg2);
    gemm_relu_pool_kernel<<<N_NODES / 16, 256, 0, stream>>>(agg2, W2, b2, Wd, gids, graph_sum);

    final_kernel<<<1, 64, 0, stream>>>(graph_sum, graph_cnt, bd, out);
}

// Round 14
// 168.149 us; speedup vs baseline: 1.2772x; 1.0136x over previous
//
#include <hip/hip_runtime.h>
#include <hip/hip_fp16.h>

#define N_NODES 10000
#define N_EDGES 640000
#define N_GRAPHS 64
#define FEATS 128

#define NSLICE 64
#define EPS (N_EDGES / NSLICE)   // 10000 edges per slice
#define CAP 128                  // padded per-node edge capacity (exp. max deg ~94 = mean+3.7sigma; 128 = +8sigma)
#define PRE_BLOCKS 1250          // 320000 float4 / 256

static inline size_t align_up(size_t x, size_t a) { return (x + a - 1) & ~(a - 1); }

// ---------------------------------------------------------------------------
// 1) HIST: blocks 0..63 histogram dst-slice b into counts[b][*] (ushort);
//    blocks 64..127 histogram src-slice (b-64) into scounts[b-64][*].
//    Block 0 also zero-inits graph_cnt/graph_sum (replaces the memset dispatch).
__global__ __launch_bounds__(256) void hist_kernel(const int* __restrict__ src,
                                                   const int* __restrict__ dst,
                                                   unsigned short* __restrict__ counts,
                                                   unsigned short* __restrict__ scounts,
                                                   int* __restrict__ graph_cnt,
                                                   float* __restrict__ graph_sum) {
    __shared__ int h[N_NODES];
    const int tid = threadIdx.x;
    const int b = blockIdx.x;
    if (b == 0 && tid < 2 * N_GRAPHS) {
        if (tid < N_GRAPHS) graph_cnt[tid] = 0;
        else                graph_sum[tid - N_GRAPHS] = 0.f;
    }
    const bool is_dst = (b < NSLICE);
    const int slice = is_dst ? b : b - NSLICE;
    const int* col = is_dst ? dst : src;
    unsigned short* outp = (is_dst ? counts : scounts) + slice * N_NODES;

    for (int i = tid; i < N_NODES; i += 256) h[i] = 0;
    __syncthreads();
    const int4* c4 = (const int4*)(col + slice * EPS);
    for (int i = tid; i < EPS / 4; i += 256) {
        int4 v = c4[i];
        atomicAdd(&h[v.x], 1);
        atomicAdd(&h[v.y], 1);
        atomicAdd(&h[v.z], 1);
        atomicAdd(&h[v.w], 1);
    }
    __syncthreads();
    for (int i = tid; i < N_NODES; i += 256) outp[i] = (unsigned short)h[i];
}

// ---------------------------------------------------------------------------
// 2) DEGNORM+BASE: per node n, scan ushort counts along slices into int write
//    bases seeded with n*CAP; deg_in / norms / graph counts in same pass.
//    (Prescale NOT fused: 40 blocks would throttle the stream — R12 lesson.)
__global__ __launch_bounds__(256) void degnorm_base_kernel(const unsigned short* __restrict__ counts,
                                                           const unsigned short* __restrict__ scounts,
                                                           const int* __restrict__ gids,
                                                           int* __restrict__ bases,
                                                           int* __restrict__ deg_in,
                                                           float* __restrict__ norm_src,
                                                           float* __restrict__ norm_dst,
                                                           int* __restrict__ graph_cnt) {
    __shared__ int gcnt[N_GRAPHS];
    const int tid = threadIdx.x;
    if (tid < N_GRAPHS) gcnt[tid] = 0;
    __syncthreads();
    int n = blockIdx.x * 256 + tid;
    if (n < N_NODES) {
        int run = n * CAP;
        for (int s = 0; s < NSLICE; s++) {
            int c = counts[s * N_NODES + n];
            bases[s * N_NODES + n] = run;
            run += c;
        }
        int di = run - n * CAP;
        int dou = 0;
        for (int s = 0; s < NSLICE; s++) dou += scounts[s * N_NODES + n];
        deg_in[n] = di;
        norm_dst[n] = rsqrtf((float)(di < 1 ? 1 : di));
        norm_src[n] = rsqrtf((float)(dou < 1 ? 1 : dou));
        atomicAdd(&gcnt[gids[n]], 1);
    }
    __syncthreads();
    if (tid < N_GRAPHS && gcnt[tid]) atomicAdd(&graph_cnt[tid], gcnt[tid]);
}

// ---------------------------------------------------------------------------
// 3) SCATTER+PRESCALE (independent work, one dispatch):
//    blocks 0..63: place EPS edges via LDS cursors into the padded CSR;
//    blocks 64..1313: xs = fp16(in_feat * norm_src) at full streaming width.
__global__ __launch_bounds__(256) void scatter_prescale_kernel(const int* __restrict__ src,
                                                               const int* __restrict__ dst,
                                                               const int* __restrict__ bases,
                                                               int* __restrict__ sorted_src,
                                                               const float* __restrict__ in_feat,
                                                               const float* __restrict__ norm_src,
                                                               __half* __restrict__ xs) {
    const int tid = threadIdx.x;
    if (blockIdx.x < NSLICE) {
        __shared__ int cur[N_NODES];
        const int s = blockIdx.x;
        for (int i = tid; i < N_NODES; i += 256) cur[i] = bases[s * N_NODES + i];
        __syncthreads();
        const int4* s4 = (const int4*)(src + s * EPS);
        const int4* d4 = (const int4*)(dst + s * EPS);
        for (int i = tid; i < EPS / 4; i += 256) {
            int4 sv = s4[i];
            int4 dv = d4[i];
            int p;
            p = atomicAdd(&cur[dv.x], 1); sorted_src[p] = sv.x;
            p = atomicAdd(&cur[dv.y], 1); sorted_src[p] = sv.y;
            p = atomicAdd(&cur[dv.z], 1); sorted_src[p] = sv.z;
            p = atomicAdd(&cur[dv.w], 1); sorted_src[p] = sv.w;
        }
    } else {
        int i = (blockIdx.x - NSLICE) * 256 + tid;  // over 320000 float4
        if (i < N_NODES * (FEATS / 4)) {
            int n = i >> 5;
            float4 v = ((const float4*)in_feat)[i];
            float s = norm_src[n];
            __half2 h0 = __floats2half2_rn(v.x * s, v.y * s);
            __half2 h1 = __floats2half2_rn(v.z * s, v.w * s);
            __half2* o = (__half2*)(xs + (size_t)i * 4);
            o[0] = h0; o[1] = h1;
        }
    }
}

// ---------------------------------------------------------------------------
// 4) AGGREGATE (fp16 in, fp32 accumulate, fp16 out): one wave per dst node.
//    Quarter-wave (16 lanes x 16 B) fetches one 256 B fp16 row per instr ->
//    4 edges per wave instruction; unroll x4 keeps 16 rows in flight/wave.
__global__ __launch_bounds__(256) void aggregate_kernel(const __half* __restrict__ X,
                                                        const int* __restrict__ sorted_src,
                                                        const int* __restrict__ deg_in,
                                                        const float* __restrict__ norm_dst,
                                                        __half* __restrict__ out) {
    const int tid = threadIdx.x;
    const int wave = tid >> 6, lane = tid & 63;
    const int grp = lane >> 4, l16 = lane & 15;
    const int n = blockIdx.x * 4 + wave;
    const int start = n * CAP;
    const int cnt = deg_in[n];
    const uint4* __restrict__ x4 = (const uint4*)X;  // row = 16 uint4 (256 B)
    float acc[8] = {0.f, 0.f, 0.f, 0.f, 0.f, 0.f, 0.f, 0.f};

    // group `grp` handles edges congruent to `grp` (mod 4)
    int c = grp;
    for (; c + 12 < cnt; c += 16) {
        int idx[4];
#pragma unroll
        for (int k = 0; k < 4; k++) idx[k] = sorted_src[start + c + 4 * k];
        uint4 v[4];
#pragma unroll
        for (int k = 0; k < 4; k++) v[k] = x4[idx[k] * 16 + l16];
#pragma unroll
        for (int k = 0; k < 4; k++) {
            const __half2* hp = (const __half2*)&v[k];
#pragma unroll
            for (int j = 0; j < 4; j++) {
                float2 f = __half22float2(hp[j]);
                acc[2 * j]     += f.x;
                acc[2 * j + 1] += f.y;
            }
        }
    }
    for (; c < cnt; c += 4) {
        uint4 v = x4[sorted_src[start + c] * 16 + l16];
        const __half2* hp = (const __half2*)&v;
#pragma unroll
        for (int j = 0; j < 4; j++) {
            float2 f = __half22float2(hp[j]);
            acc[2 * j]     += f.x;
            acc[2 * j + 1] += f.y;
        }
    }
    // combine the 4 groups (same feature columns in all groups)
#pragma unroll
    for (int j = 0; j < 8; j++) {
        acc[j] += __shfl_xor(acc[j], 16);
        acc[j] += __shfl_xor(acc[j], 32);
    }
    if (grp == 0) {
        const float nd = norm_dst[n];
        __half2 o[4];
#pragma unroll
        for (int j = 0; j < 4; j++)
            o[j] = __floats2half2_rn(acc[2 * j] * nd, acc[2 * j + 1] * nd);
        *(uint4*)(out + (size_t)n * FEATS + l16 * 8) = *(const uint4*)o;
    }
}

// ---------------------------------------------------------------------------
// A-tile staging: 16 fp16 rows -> LDS fp32. 256 threads x 1 uint4 (8 halves).
__device__ __forceinline__ void stage_fp16_tile(const __half* __restrict__ A,
                                                int nb, int tid, float* As) {
    const int row = tid >> 4, c16 = tid & 15;
    uint4 v = *(const uint4*)(A + (size_t)(nb + row) * FEATS + c16 * 8);
    const __half2* hp = (const __half2*)&v;
    float* dst = As + row * FEATS + c16 * 8;
#pragma unroll
    for (int j = 0; j < 4; j++) {
        float2 f = __half22float2(hp[j]);
        dst[2 * j]     = f.x;
        dst[2 * j + 1] = f.y;
    }
}

// ---------------------------------------------------------------------------
// 5) GEMM1: h = fp16(norm_src ⊙ relu(A @ W + b))
__global__ __launch_bounds__(256) void gemm_relu_scale_kernel(const __half* __restrict__ A,
                                                              const float* __restrict__ W,
                                                              const float* __restrict__ bias,
                                                              const float* __restrict__ scale,
                                                              __half* __restrict__ out) {
    __shared__ float As[16 * FEATS];
    int tid = threadIdx.x;
    int nb = blockIdx.x * 16;
    stage_fp16_tile(A, nb, tid, As);
    __syncthreads();
    int fg = (tid & 31) << 2;
    int r  = tid >> 5;
    const float* a0p = As + r * FEATS;
    const float* a1p = As + (r + 8) * FEATS;
    float4 acc0 = make_float4(0.f, 0.f, 0.f, 0.f);
    float4 acc1 = make_float4(0.f, 0.f, 0.f, 0.f);
#pragma unroll 4
    for (int k = 0; k < FEATS; k++) {
        float a0 = a0p[k];
        float a1 = a1p[k];
        float4 w = *(const float4*)(W + k * FEATS + fg);
        acc0.x = fmaf(a0, w.x, acc0.x); acc0.y = fmaf(a0, w.y, acc0.y);
        acc0.z = fmaf(a0, w.z, acc0.z); acc0.w = fmaf(a0, w.w, acc0.w);
        acc1.x = fmaf(a1, w.x, acc1.x); acc1.y = fmaf(a1, w.y, acc1.y);
        acc1.z = fmaf(a1, w.z, acc1.z); acc1.w = fmaf(a1, w.w, acc1.w);
    }
    float4 bb = *(const float4*)(bias + fg);
    int gn0 = nb + r, gn1 = nb + r + 8;
    float s0 = scale[gn0], s1 = scale[gn1];
    __half2 h00 = __floats2half2_rn(fmaxf(acc0.x + bb.x, 0.f) * s0,
                                    fmaxf(acc0.y + bb.y, 0.f) * s0);
    __half2 h01 = __floats2half2_rn(fmaxf(acc0.z + bb.z, 0.f) * s0,
                                    fmaxf(acc0.w + bb.w, 0.f) * s0);
    __half2 h10 = __floats2half2_rn(fmaxf(acc1.x + bb.x, 0.f) * s1,
                                    fmaxf(acc1.y + bb.y, 0.f) * s1);
    __half2 h11 = __floats2half2_rn(fmaxf(acc1.z + bb.z, 0.f) * s1,
                                    fmaxf(acc1.w + bb.w, 0.f) * s1);
    __half2* o0 = (__half2*)(out + (size_t)gn0 * FEATS + fg);
    __half2* o1 = (__half2*)(out + (size_t)gn1 * FEATS + fg);
    o0[0] = h00; o0[1] = h01;
    o1[0] = h10; o1[1] = h11;
}

// ---------------------------------------------------------------------------
// 6) GEMM2+POOL: per node s = relu(A@W2+b2) . Wd ; LDS 64-bin accumulate,
//    then few global atomics per block. No device-scope fence (R11 lesson).
__global__ __launch_bounds__(256) void gemm_relu_pool_kernel(const __half* __restrict__ A,
                                                             const float* __restrict__ W,
                                                             const float* __restrict__ bias,
                                                             const float* __restrict__ Wd,
                                                             const int* __restrict__ gids,
                                                             float* __restrict__ graph_sum) {
    __shared__ float As[16 * FEATS];
    __shared__ float bins[N_GRAPHS];
    int tid = threadIdx.x;
    int nb = blockIdx.x * 16;
    stage_fp16_tile(A, nb, tid, As);
    if (tid < N_GRAPHS) bins[tid] = 0.f;
    __syncthreads();
    int fg = (tid & 31) << 2;
    int r  = tid >> 5;
    const float* a0p = As + r * FEATS;
    const float* a1p = As + (r + 8) * FEATS;
    float4 acc0 = make_float4(0.f, 0.f, 0.f, 0.f);
    float4 acc1 = make_float4(0.f, 0.f, 0.f, 0.f);
#pragma unroll 4
    for (int k = 0; k < FEATS; k++) {
        float a0 = a0p[k];
        float a1 = a1p[k];
        float4 w = *(const float4*)(W + k * FEATS + fg);
        acc0.x = fmaf(a0, w.x, acc0.x); acc0.y = fmaf(a0, w.y, acc0.y);
        acc0.z = fmaf(a0, w.z, acc0.z); acc0.w = fmaf(a0, w.w, acc0.w);
        acc1.x = fmaf(a1, w.x, acc1.x); acc1.y = fmaf(a1, w.y, acc1.y);
        acc1.z = fmaf(a1, w.z, acc1.z); acc1.w = fmaf(a1, w.w, acc1.w);
    }
    float4 bb = *(const float4*)(bias + fg);
    float4 wd = *(const float4*)(Wd + fg);
    float p0 = fmaxf(acc0.x + bb.x, 0.f) * wd.x + fmaxf(acc0.y + bb.y, 0.f) * wd.y +
               fmaxf(acc0.z + bb.z, 0.f) * wd.z + fmaxf(acc0.w + bb.w, 0.f) * wd.w;
    float p1 = fmaxf(acc1.x + bb.x, 0.f) * wd.x + fmaxf(acc1.y + bb.y, 0.f) * wd.y +
               fmaxf(acc1.z + bb.z, 0.f) * wd.z + fmaxf(acc1.w + bb.w, 0.f) * wd.w;
#pragma unroll
    for (int d = 16; d >= 1; d >>= 1) {
        p0 += __shfl_down(p0, d);
        p1 += __shfl_down(p1, d);
    }
    if ((tid & 31) == 0) {
        int gn0 = nb + r, gn1 = nb + r + 8;
        atomicAdd(&bins[gids[gn0]], p0);
        atomicAdd(&bins[gids[gn1]], p1);
    }
    __syncthreads();
    if (tid < N_GRAPHS) {
        float v = bins[tid];
        if (v != 0.f) atomicAdd(&graph_sum[tid], v);
    }
}

// ---------------------------------------------------------------------------
// 7) final: out[g] = graph_sum[g] / max(cnt,1) + bd
__global__ __launch_bounds__(64) void final_kernel(const float* __restrict__ graph_sum,
                                                   const int* __restrict__ graph_cnt,
                                                   const float* __restrict__ bd,
                                                   float* __restrict__ out) {
    int g = threadIdx.x;
    if (g < N_GRAPHS) {
        out[g] = graph_sum[g] / fmaxf((float)graph_cnt[g], 1.f) + bd[0];
    }
}

// ---------------------------------------------------------------------------
extern "C" void kernel_launch(void* const* d_in, const int* in_sizes, int n_in,
                              void* d_out, int out_size, void* d_ws, size_t ws_size,
                              hipStream_t stream) {
    const float* in_feat = (const float*)d_in[0];
    const int*   src     = (const int*)d_in[1];
    const int*   dst     = (const int*)d_in[2];
    const int*   gids    = (const int*)d_in[3];
    const float* W1      = (const float*)d_in[4];
    const float* b1      = (const float*)d_in[5];
    const float* W2      = (const float*)d_in[6];
    const float* b2      = (const float*)d_in[7];
    const float* Wd      = (const float*)d_in[8];
    const float* bd      = (const float*)d_in[9];
    float* out = (float*)d_out;

    char* ws = (char*)d_ws;
    size_t off = 0;
    int* graph_cnt = (int*)(ws + off); off += N_GRAPHS * 4;
    float* graph_sum = (float*)(ws + off); off += N_GRAPHS * 4;
    off = align_up(off, 512);
    unsigned short* counts  = (unsigned short*)(ws + off); off += (size_t)NSLICE * N_NODES * 2; // 1.28 MB
    off = align_up(off, 512);
    unsigned short* scounts = (unsigned short*)(ws + off); off += (size_t)NSLICE * N_NODES * 2; // 1.28 MB
    off = align_up(off, 512);
    int* bases = (int*)(ws + off); off += (size_t)NSLICE * N_NODES * 4;     // 2.56 MB
    off = align_up(off, 512);
    int* deg_in  = (int*)(ws + off); off += N_NODES * 4;
    off = align_up(off, 512);
    float* norm_src = (float*)(ws + off); off += N_NODES * 4;
    off = align_up(off, 512);
    float* norm_dst = (float*)(ws + off); off += N_NODES * 4;
    off = align_up(off, 512);
    int* sorted_src = (int*)(ws + off); off += (size_t)N_NODES * CAP * 4 + 4096;  // 5.12 MB
    off = align_up(off, 512);
    __half* xs   = (__half*)(ws + off); off += (size_t)N_NODES * FEATS * 2; // 2.56 MB
    off = align_up(off, 512);
    __half* h    = (__half*)(ws + off); off += (size_t)N_NODES * FEATS * 2; // 2.56 MB
    off = align_up(off, 512);
    __half* agg1 = (__half*)(ws + off); off += (size_t)N_NODES * FEATS * 2; // 2.56 MB
    off = align_up(off, 512);
    __half* agg2 = (__half*)(ws + off); off += (size_t)N_NODES * FEATS * 2; // 2.56 MB
    (void)ws_size; // ~21 MB used

    hist_kernel<<<2 * NSLICE, 256, 0, stream>>>(src, dst, counts, scounts,
                                                graph_cnt, graph_sum);
    degnorm_base_kernel<<<(N_NODES + 255) / 256, 256, 0, stream>>>(counts, scounts, gids,
                                                                   bases, deg_in, norm_src,
                                                                   norm_dst, graph_cnt);
    scatter_prescale_kernel<<<NSLICE + PRE_BLOCKS, 256, 0, stream>>>(src, dst, bases,
                                                                     sorted_src, in_feat,
                                                                     norm_src, xs);

    // layer 1 (h is written pre-scaled by norm_src, fp16, for layer 2)
    aggregate_kernel<<<N_NODES / 4, 256, 0, stream>>>(xs, sorted_src, deg_in, norm_dst, agg1);
    gemm_relu_scale_kernel<<<N_NODES / 16, 256, 0, stream>>>(agg1, W1, b1, norm_src, h);

    // layer 2 (+ fused pool)
    aggregate_kernel<<<N_NODES / 4, 256, 0, stream>>>(h, sorted_src, deg_in, norm_dst, agg2);
    gemm_relu_pool_kernel<<<N_NODES / 16, 256, 0, stream>>>(agg2, W2, b2, Wd, gids, graph_sum);

    final_kernel<<<1, 64, 0, stream>>>(graph_sum, graph_cnt, bd, out);
}